// Round 1
// baseline (653.811 us; speedup 1.0000x reference)
//
#include <hip/hip_runtime.h>
#include <hip/hip_bf16.h>
#include <math.h>

// Problem constants
#define B2      128
#define NSEQ    256
#define DMODEL  256
#define NHEAD   8
#define CDIM    32
#define HC      256          // NHEAD*CDIM
#define NROWS   (B2*NSEQ)    // 32768
#define SCALING 0.17677669529663687f  // 1/sqrt(32)

// ---------------- Kernel 1: fused QKV + gate projection ----------------
// Computes P = X @ concat(w_qkv, w_gate)^T  (M=32768, N=1024, K=256)
// Scatters q (scaled), k, v into per-head layout [b2][h][n][c]; gate with
// sigmoid into [row][hc].
#define BM 64
#define BN 64
#define BK 16

__global__ __launch_bounds__(256) void qkvg_gemm_kernel(
    const float* __restrict__ X,      // [32768][256]
    const float* __restrict__ Wqkv,   // [768][256]
    const float* __restrict__ Wg,     // [256][256]
    const float* __restrict__ gbias,  // [256]
    float* __restrict__ q_ws,         // [128*8*256*32]
    float* __restrict__ k_ws,
    float* __restrict__ v_ws,
    float* __restrict__ g_ws)         // [32768][256]
{
    __shared__ float As[BK][BM + 4];
    __shared__ float Bs[BK][BN + 4];

    const int m0   = blockIdx.x * BM;
    const int nblk = blockIdx.y;   // 0..15 over 1024 output cols
    const float* Wbase;
    int wrow0;
    if (nblk < 12) { Wbase = Wqkv; wrow0 = nblk * 64; }
    else           { Wbase = Wg;   wrow0 = nblk * 64 - 768; }

    const int t  = threadIdx.x;
    const int tx = t & 15;
    const int ty = t >> 4;

    float acc[4][4];
    #pragma unroll
    for (int i = 0; i < 4; ++i)
        #pragma unroll
        for (int j = 0; j < 4; ++j) acc[i][j] = 0.f;

    const int lm  = t >> 2;        // 0..63
    const int lk4 = (t & 3) * 4;   // 0,4,8,12

    for (int k0 = 0; k0 < DMODEL; k0 += BK) {
        {
            float4 v = *(const float4*)(X + (size_t)(m0 + lm) * DMODEL + k0 + lk4);
            As[lk4 + 0][lm] = v.x; As[lk4 + 1][lm] = v.y;
            As[lk4 + 2][lm] = v.z; As[lk4 + 3][lm] = v.w;
        }
        {
            float4 v = *(const float4*)(Wbase + (size_t)(wrow0 + lm) * DMODEL + k0 + lk4);
            Bs[lk4 + 0][lm] = v.x; Bs[lk4 + 1][lm] = v.y;
            Bs[lk4 + 2][lm] = v.z; Bs[lk4 + 3][lm] = v.w;
        }
        __syncthreads();
        #pragma unroll
        for (int k = 0; k < BK; ++k) {
            float4 av = *(const float4*)&As[k][ty * 4];
            float4 bv = *(const float4*)&Bs[k][tx * 4];
            float a[4] = {av.x, av.y, av.z, av.w};
            float b[4] = {bv.x, bv.y, bv.z, bv.w};
            #pragma unroll
            for (int i = 0; i < 4; ++i)
                #pragma unroll
                for (int j = 0; j < 4; ++j)
                    acc[i][j] = fmaf(a[i], b[j], acc[i][j]);
        }
        __syncthreads();
    }

    const int gn0 = nblk * 64;
    #pragma unroll
    for (int i = 0; i < 4; ++i) {
        const int r  = m0 + ty * 4 + i;
        const int b2 = r >> 8;
        const int n  = r & 255;
        #pragma unroll
        for (int j = 0; j < 4; ++j) {
            const int e = gn0 + tx * 4 + j;
            float val = acc[i][j];
            if (e < 256) {
                int h = e >> 5, c = e & 31;
                q_ws[(((size_t)(b2 * NHEAD + h) * NSEQ + n) * CDIM) + c] = val * SCALING;
            } else if (e < 512) {
                int e2 = e - 256, h = e2 >> 5, c = e2 & 31;
                k_ws[(((size_t)(b2 * NHEAD + h) * NSEQ + n) * CDIM) + c] = val;
            } else if (e < 768) {
                int e2 = e - 512, h = e2 >> 5, c = e2 & 31;
                v_ws[(((size_t)(b2 * NHEAD + h) * NSEQ + n) * CDIM) + c] = val;
            } else {
                int c = e - 768;
                float z = val + gbias[c];
                g_ws[(size_t)r * HC + c] = 1.f / (1.f + __expf(-z));
            }
        }
    }
}

// ---------------- Kernel 2: per-(b2,head) attention ----------------
// One block (256 threads) per (b2, h). Thread i owns query row i.
__global__ __launch_bounds__(256) void attn_kernel(
    const float* __restrict__ q_ws,
    const float* __restrict__ k_ws,
    const float* __restrict__ v_ws,
    const float* __restrict__ g_ws,
    const float* __restrict__ bias,   // [8][256][256]
    const float* __restrict__ mask,   // [128][256]
    float* __restrict__ wa_ws)        // [32768][256] gated weighted avg
{
    __shared__ float Ks[NSEQ][CDIM];
    __shared__ float Vs[NSEQ][CDIM];

    const int bh = blockIdx.x;     // b2*8 + h
    const int b2 = bh >> 3;
    const int h  = bh & 7;
    const int t  = threadIdx.x;    // query row

    const size_t base = (size_t)bh * NSEQ * CDIM;

    #pragma unroll
    for (int c4 = 0; c4 < CDIM; c4 += 4) {
        *(float4*)&Ks[t][c4] = *(const float4*)(k_ws + base + (size_t)t * CDIM + c4);
        *(float4*)&Vs[t][c4] = *(const float4*)(v_ws + base + (size_t)t * CDIM + c4);
    }

    float q[CDIM];
    #pragma unroll
    for (int c4 = 0; c4 < CDIM; c4 += 4) {
        float4 v = *(const float4*)(q_ws + base + (size_t)t * CDIM + c4);
        q[c4] = v.x; q[c4 + 1] = v.y; q[c4 + 2] = v.z; q[c4 + 3] = v.w;
    }
    __syncthreads();

    const float* brow = bias + ((size_t)h * NSEQ + t) * NSEQ;
    const float* mrow = mask + (size_t)b2 * NSEQ;

    // pass 1: row max
    float mx = -1e30f;
    for (int j = 0; j < NSEQ; ++j) {
        float l = 0.f;
        #pragma unroll
        for (int c4 = 0; c4 < CDIM; c4 += 4) {
            float4 kv = *(const float4*)&Ks[j][c4];
            l = fmaf(q[c4], kv.x, l);
            l = fmaf(q[c4 + 1], kv.y, l);
            l = fmaf(q[c4 + 2], kv.z, l);
            l = fmaf(q[c4 + 3], kv.w, l);
        }
        l += brow[j] + (mrow[j] - 1.f) * 1e9f;
        mx = fmaxf(mx, l);
    }

    // pass 2: exp + PV accumulate
    float s = 0.f;
    float wa[CDIM];
    #pragma unroll
    for (int c = 0; c < CDIM; ++c) wa[c] = 0.f;

    for (int j = 0; j < NSEQ; ++j) {
        float l = 0.f;
        #pragma unroll
        for (int c4 = 0; c4 < CDIM; c4 += 4) {
            float4 kv = *(const float4*)&Ks[j][c4];
            l = fmaf(q[c4], kv.x, l);
            l = fmaf(q[c4 + 1], kv.y, l);
            l = fmaf(q[c4 + 2], kv.z, l);
            l = fmaf(q[c4 + 3], kv.w, l);
        }
        l += brow[j] + (mrow[j] - 1.f) * 1e9f;
        float e = __expf(l - mx);
        s += e;
        #pragma unroll
        for (int c4 = 0; c4 < CDIM; c4 += 4) {
            float4 vv = *(const float4*)&Vs[j][c4];
            wa[c4]     = fmaf(e, vv.x, wa[c4]);
            wa[c4 + 1] = fmaf(e, vv.y, wa[c4 + 1]);
            wa[c4 + 2] = fmaf(e, vv.z, wa[c4 + 2]);
            wa[c4 + 3] = fmaf(e, vv.w, wa[c4 + 3]);
        }
    }

    const float inv = 1.f / s;
    const size_t r = (size_t)b2 * NSEQ + t;
    #pragma unroll
    for (int c4 = 0; c4 < CDIM; c4 += 4) {
        float4 g = *(const float4*)(g_ws + r * HC + h * CDIM + c4);
        float4 o;
        o.x = wa[c4]     * inv * g.x;
        o.y = wa[c4 + 1] * inv * g.y;
        o.z = wa[c4 + 2] * inv * g.z;
        o.w = wa[c4 + 3] * inv * g.w;
        *(float4*)(wa_ws + r * HC + h * CDIM + c4) = o;
    }
}

// ---------------- Kernel 3: output projection ----------------
// out = WA @ w_o^T + b_o  (M=32768, N=256, K=256)
__global__ __launch_bounds__(256) void out_gemm_kernel(
    const float* __restrict__ WA,    // [32768][256]
    const float* __restrict__ Wo,    // [256][256]
    const float* __restrict__ bo,    // [256]
    float* __restrict__ out)         // [32768][256]
{
    __shared__ float As[BK][BM + 4];
    __shared__ float Bs[BK][BN + 4];

    const int m0 = blockIdx.x * BM;
    const int n0 = blockIdx.y * BN;

    const int t  = threadIdx.x;
    const int tx = t & 15;
    const int ty = t >> 4;

    float acc[4][4];
    #pragma unroll
    for (int i = 0; i < 4; ++i)
        #pragma unroll
        for (int j = 0; j < 4; ++j) acc[i][j] = 0.f;

    const int lm  = t >> 2;
    const int lk4 = (t & 3) * 4;

    for (int k0 = 0; k0 < HC; k0 += BK) {
        {
            float4 v = *(const float4*)(WA + (size_t)(m0 + lm) * HC + k0 + lk4);
            As[lk4 + 0][lm] = v.x; As[lk4 + 1][lm] = v.y;
            As[lk4 + 2][lm] = v.z; As[lk4 + 3][lm] = v.w;
        }
        {
            float4 v = *(const float4*)(Wo + (size_t)(n0 + lm) * HC + k0 + lk4);
            Bs[lk4 + 0][lm] = v.x; Bs[lk4 + 1][lm] = v.y;
            Bs[lk4 + 2][lm] = v.z; Bs[lk4 + 3][lm] = v.w;
        }
        __syncthreads();
        #pragma unroll
        for (int k = 0; k < BK; ++k) {
            float4 av = *(const float4*)&As[k][ty * 4];
            float4 bv = *(const float4*)&Bs[k][tx * 4];
            float a[4] = {av.x, av.y, av.z, av.w};
            float b[4] = {bv.x, bv.y, bv.z, bv.w};
            #pragma unroll
            for (int i = 0; i < 4; ++i)
                #pragma unroll
                for (int j = 0; j < 4; ++j)
                    acc[i][j] = fmaf(a[i], b[j], acc[i][j]);
        }
        __syncthreads();
    }

    #pragma unroll
    for (int i = 0; i < 4; ++i) {
        const int r = m0 + ty * 4 + i;
        const int n = n0 + tx * 4;
        float4 o;
        o.x = acc[i][0] + bo[n + 0];
        o.y = acc[i][1] + bo[n + 1];
        o.z = acc[i][2] + bo[n + 2];
        o.w = acc[i][3] + bo[n + 3];
        *(float4*)(out + (size_t)r * HC + n) = o;
    }
}

extern "C" void kernel_launch(void* const* d_in, const int* in_sizes, int n_in,
                              void* d_out, int out_size, void* d_ws, size_t ws_size,
                              hipStream_t stream) {
    const float* in_data = (const float*)d_in[0];   // [1,128,256,256]
    const float* mask    = (const float*)d_in[1];   // [1,128,256]
    const float* nb_bias = (const float*)d_in[2];   // [1,8,256,256]
    const float* w_qkv   = (const float*)d_in[3];   // [768,256]
    const float* w_gate  = (const float*)d_in[4];   // [256,256]
    const float* g_bias  = (const float*)d_in[5];   // [256]
    const float* w_o     = (const float*)d_in[6];   // [256,256]
    const float* b_o     = (const float*)d_in[7];   // [256]
    float* out = (float*)d_out;

    // workspace layout (floats)
    float* ws = (float*)d_ws;
    const size_t per_head = (size_t)B2 * NHEAD * NSEQ * CDIM;  // 8,388,608
    float* q_ws  = ws;
    float* k_ws  = q_ws + per_head;
    float* v_ws  = k_ws + per_head;
    float* g_ws  = v_ws + per_head;                 // [32768][256]
    float* wa_ws = g_ws + (size_t)NROWS * HC;       // [32768][256]

    // Kernel 1: QKV + gate projection
    qkvg_gemm_kernel<<<dim3(NROWS / BM, 1024 / BN), 256, 0, stream>>>(
        in_data, w_qkv, w_gate, g_bias, q_ws, k_ws, v_ws, g_ws);

    // Kernel 2: attention
    attn_kernel<<<dim3(B2 * NHEAD), 256, 0, stream>>>(
        q_ws, k_ws, v_ws, g_ws, nb_bias, mask, wa_ws);

    // Kernel 3: output projection
    out_gemm_kernel<<<dim3(NROWS / BM, HC / BN), 256, 0, stream>>>(
        wa_ws, w_o, b_o, out);
}

// Round 2
// 323.065 us; speedup vs baseline: 2.0238x; 2.0238x over previous
//
#include <hip/hip_runtime.h>
#include <hip/hip_bf16.h>
#include <math.h>

// Problem constants
#define B2      128
#define NSEQ    256
#define DMODEL  256
#define NHEAD   8
#define CDIM    32
#define HC      256          // NHEAD*CDIM
#define NROWS   (B2*NSEQ)    // 32768
#define SCALING 0.17677669529663687f  // 1/sqrt(32)

typedef __attribute__((ext_vector_type(8))) short bf16x8;
typedef __attribute__((ext_vector_type(4))) float f32x4;

static __device__ __forceinline__ ushort f2bf(float f) {
    __hip_bfloat16 b = __float2bfloat16(f);
    ushort r; __builtin_memcpy(&r, &b, 2); return r;
}
static __device__ __forceinline__ float bf2f(ushort u) {
    __hip_bfloat16 b; __builtin_memcpy(&b, &u, 2); return __bfloat162float(b);
}

// ---------------- Kernel 1: fused QKV + gate projection ----------------
// P = X @ concat(w_qkv, w_gate)^T  (M=32768, N=1024, K=256), fp32 math,
// bf16 outputs scattered into per-head q/k/v layout + sigmoid gate.
#define BM 64
#define BN 64
#define BK 16

__global__ __launch_bounds__(256) void qkvg_gemm_kernel(
    const float* __restrict__ X,      // [32768][256]
    const float* __restrict__ Wqkv,   // [768][256]
    const float* __restrict__ Wg,     // [256][256]
    const float* __restrict__ gbias,  // [256]
    ushort* __restrict__ q_ws,        // bf16 [128*8][256][32]
    ushort* __restrict__ k_ws,
    ushort* __restrict__ v_ws,
    ushort* __restrict__ g_ws)        // bf16 [32768][256]
{
    __shared__ float As[BK][BM + 4];
    __shared__ float Bs[BK][BN + 4];

    const int m0   = blockIdx.x * BM;
    const int nblk = blockIdx.y;   // 0..15 over 1024 output cols
    const float* Wbase;
    int wrow0;
    if (nblk < 12) { Wbase = Wqkv; wrow0 = nblk * 64; }
    else           { Wbase = Wg;   wrow0 = nblk * 64 - 768; }

    const int t  = threadIdx.x;
    const int tx = t & 15;
    const int ty = t >> 4;

    float acc[4][4];
    #pragma unroll
    for (int i = 0; i < 4; ++i)
        #pragma unroll
        for (int j = 0; j < 4; ++j) acc[i][j] = 0.f;

    const int lm  = t >> 2;        // 0..63
    const int lk4 = (t & 3) * 4;   // 0,4,8,12

    for (int k0 = 0; k0 < DMODEL; k0 += BK) {
        {
            float4 v = *(const float4*)(X + (size_t)(m0 + lm) * DMODEL + k0 + lk4);
            As[lk4 + 0][lm] = v.x; As[lk4 + 1][lm] = v.y;
            As[lk4 + 2][lm] = v.z; As[lk4 + 3][lm] = v.w;
        }
        {
            float4 v = *(const float4*)(Wbase + (size_t)(wrow0 + lm) * DMODEL + k0 + lk4);
            Bs[lk4 + 0][lm] = v.x; Bs[lk4 + 1][lm] = v.y;
            Bs[lk4 + 2][lm] = v.z; Bs[lk4 + 3][lm] = v.w;
        }
        __syncthreads();
        #pragma unroll
        for (int k = 0; k < BK; ++k) {
            float4 av = *(const float4*)&As[k][ty * 4];
            float4 bv = *(const float4*)&Bs[k][tx * 4];
            float a[4] = {av.x, av.y, av.z, av.w};
            float b[4] = {bv.x, bv.y, bv.z, bv.w};
            #pragma unroll
            for (int i = 0; i < 4; ++i)
                #pragma unroll
                for (int j = 0; j < 4; ++j)
                    acc[i][j] = fmaf(a[i], b[j], acc[i][j]);
        }
        __syncthreads();
    }

    const int gn0 = nblk * 64;
    #pragma unroll
    for (int i = 0; i < 4; ++i) {
        const int r  = m0 + ty * 4 + i;
        const int b2 = r >> 8;
        const int n  = r & 255;
        const int e0 = gn0 + tx * 4;   // block-uniform segment (64 | 256)
        union { ushort u[4]; uint2 v; } pk;
        ushort* dst;
        if (e0 < 256) {
            const int hh = e0 >> 5, c0 = e0 & 31;
            #pragma unroll
            for (int j = 0; j < 4; ++j) pk.u[j] = f2bf(acc[i][j] * SCALING);
            dst = q_ws + ((size_t)(b2 * 8 + hh) * 256 + n) * 32 + c0;
        } else if (e0 < 512) {
            const int e2 = e0 - 256, hh = e2 >> 5, c0 = e2 & 31;
            #pragma unroll
            for (int j = 0; j < 4; ++j) pk.u[j] = f2bf(acc[i][j]);
            dst = k_ws + ((size_t)(b2 * 8 + hh) * 256 + n) * 32 + c0;
        } else if (e0 < 768) {
            const int e2 = e0 - 512, hh = e2 >> 5, c0 = e2 & 31;
            #pragma unroll
            for (int j = 0; j < 4; ++j) pk.u[j] = f2bf(acc[i][j]);
            dst = v_ws + ((size_t)(b2 * 8 + hh) * 256 + n) * 32 + c0;
        } else {
            const int c0 = e0 - 768;
            #pragma unroll
            for (int j = 0; j < 4; ++j) {
                float z = acc[i][j] + gbias[c0 + j];
                pk.u[j] = f2bf(1.f / (1.f + __expf(-z)));
            }
            dst = g_ws + (size_t)r * 256 + c0;
        }
        *(uint2*)dst = pk.v;
    }
}

// ---------------- Kernel 2: MFMA attention ----------------
// Block = 512 threads (8 waves), covers 128 q-rows of one (b2,h).
// Wave owns 16 q-rows. QK^T: 16 mfma_16x16x32_bf16 with bias+mask preloaded
// into C. In-register softmax (rows live in C-layout lanes). P transposed to
// A-frag layout via per-wave swizzled LDS chunk. PV: 16 mfma vs transposed V.
#define SWZ(c) ((((c) >> 2) & 3) << 5)

__global__ __launch_bounds__(512) void attn_mfma_kernel(
    const ushort* __restrict__ q_ws,
    const ushort* __restrict__ k_ws,
    const ushort* __restrict__ v_ws,
    const ushort* __restrict__ g_ws,
    const float* __restrict__ bias,   // [8][256][256]
    const float* __restrict__ mask,   // [128][256]
    ushort* __restrict__ wa_ws)       // bf16 [32768][256]
{
    __shared__ ushort Ks[256 * 32];   // [n][c] row-major, 16KB
    __shared__ ushort Vt[32 * 256];   // [c][n] transposed, swizzled, 16KB
    __shared__ ushort Pl[8 * 16 * 64];// per-wave P chunk [16][64], swizzled

    const int tid  = threadIdx.x;
    const int bh   = blockIdx.x >> 1;  // b2*8 + h
    const int half = blockIdx.x & 1;
    const int b2   = bh >> 3;
    const int h    = bh & 7;
    const int w    = tid >> 6;
    const int lane = tid & 63;
    const int lj   = lane & 15;
    const int lg   = lane >> 4;

    // ---- stage K: linear 16KB copy (coalesced global, uniform LDS granules)
    {
        const uint4* gk = (const uint4*)(k_ws + (size_t)bh * 8192);
        uint4* sk = (uint4*)Ks;
        sk[tid]       = gk[tid];
        sk[tid + 512] = gk[tid + 512];
    }
    // ---- stage V transposed: Vt[c][n] = V[n][c], swizzled rows
    {
        const int cq = tid & 3;
        #pragma unroll
        for (int it = 0; it < 2; ++it) {
            const int n = it * 128 + (tid >> 2);
            uint4 v = *(const uint4*)(v_ws + (size_t)bh * 8192 + n * 32 + cq * 8);
            const ushort* pv = (const ushort*)&v;
            #pragma unroll
            for (int e = 0; e < 8; ++e) {
                const int c = cq * 8 + e;
                const int byte = c * 512 + ((2 * n) ^ SWZ(c));
                Vt[byte >> 1] = pv[e];
            }
        }
    }

    // ---- Q fragment (A layout: row = lane&15, k = (lane>>4)*8..+7)
    const int q0 = half * 128 + w * 16;
    const bf16x8 qf = *(const bf16x8*)(q_ws + (size_t)bh * 8192 + (size_t)(q0 + lj) * 32 + lg * 8);

    __syncthreads();

    // ---- accumulator init: bias + mask (C-operand of mfma)
    f32x4 acc[16];
    const float* bbase = bias + (size_t)h * 256 * 256;
    const float* mrow  = mask + (size_t)b2 * 256;
    #pragma unroll
    for (int t = 0; t < 16; ++t) {
        const int col = t * 16 + lj;
        const float mterm = (mrow[col] - 1.0f) * 1e9f;
        #pragma unroll
        for (int r = 0; r < 4; ++r) {
            const int qrow = q0 + lg * 4 + r;
            acc[t][r] = bbase[(size_t)qrow * 256 + col] + mterm;
        }
    }

    // ---- QK^T: 16 mfma, B-frag = K rows read contiguous from LDS
    #pragma unroll
    for (int t = 0; t < 16; ++t) {
        const bf16x8 kf = *(const bf16x8*)(Ks + (t * 16 + lj) * 32 + lg * 8);
        acc[t] = __builtin_amdgcn_mfma_f32_16x16x32_bf16(qf, kf, acc[t], 0, 0, 0);
    }

    // ---- softmax fully in-register (row r lives in lanes with same lg)
    float inv[4];
    #pragma unroll
    for (int r = 0; r < 4; ++r) {
        float m = acc[0][r];
        #pragma unroll
        for (int t = 1; t < 16; ++t) m = fmaxf(m, acc[t][r]);
        m = fmaxf(m, __shfl_xor(m, 1));
        m = fmaxf(m, __shfl_xor(m, 2));
        m = fmaxf(m, __shfl_xor(m, 4));
        m = fmaxf(m, __shfl_xor(m, 8));
        float s = 0.f;
        #pragma unroll
        for (int t = 0; t < 16; ++t) {
            float e = __expf(acc[t][r] - m);
            acc[t][r] = e;
            s += e;
        }
        s += __shfl_xor(s, 1);
        s += __shfl_xor(s, 2);
        s += __shfl_xor(s, 4);
        s += __shfl_xor(s, 8);
        inv[r] = 1.0f / s;
    }

    // ---- PV in 4 chunks of 64 keys: D-layout -> A-layout via per-wave LDS
    ushort* PlW = Pl + w * 1024;
    f32x4 o0 = {0.f, 0.f, 0.f, 0.f};
    f32x4 o1 = {0.f, 0.f, 0.f, 0.f};
    #pragma unroll
    for (int ch = 0; ch < 4; ++ch) {
        #pragma unroll
        for (int tt = 0; tt < 4; ++tt) {
            const int t = ch * 4 + tt;
            #pragma unroll
            for (int r = 0; r < 4; ++r) {
                const int row  = lg * 4 + r;
                const int byte = row * 128 + ((32 * tt + 2 * lj) ^ (lg << 5));
                PlW[byte >> 1] = f2bf(acc[t][r]);
            }
        }
        #pragma unroll
        for (int kk = 0; kk < 2; ++kk) {
            const int abyte = lj * 128 + ((64 * kk + 16 * lg) ^ SWZ(lj));
            const bf16x8 pa = *(const bf16x8*)(PlW + (abyte >> 1));
            const int ks = ch * 2 + kk;
            {
                const int cr = lj;
                const int vbyte = cr * 512 + ((64 * ks + 16 * lg) ^ SWZ(cr));
                const bf16x8 vb = *(const bf16x8*)(Vt + (vbyte >> 1));
                o0 = __builtin_amdgcn_mfma_f32_16x16x32_bf16(pa, vb, o0, 0, 0, 0);
            }
            {
                const int cr = 16 + lj;
                const int vbyte = cr * 512 + ((64 * ks + 16 * lg) ^ SWZ(cr));
                const bf16x8 vb = *(const bf16x8*)(Vt + (vbyte >> 1));
                o1 = __builtin_amdgcn_mfma_f32_16x16x32_bf16(pa, vb, o1, 0, 0, 0);
            }
        }
    }

    // ---- epilogue: normalize, gate, store bf16
    #pragma unroll
    for (int r = 0; r < 4; ++r) {
        const int qrow = q0 + lg * 4 + r;
        const size_t rowbase = ((size_t)(b2 * 256 + qrow)) * 256 + h * 32;
        {
            const float gv = bf2f(g_ws[rowbase + lj]);
            wa_ws[rowbase + lj] = f2bf(o0[r] * inv[r] * gv);
        }
        {
            const float gv = bf2f(g_ws[rowbase + 16 + lj]);
            wa_ws[rowbase + 16 + lj] = f2bf(o1[r] * inv[r] * gv);
        }
    }
}

// ---------------- Kernel 3: output projection ----------------
// out = WA @ w_o^T + b_o  (M=32768, N=256, K=256); WA is bf16 now.
__global__ __launch_bounds__(256) void out_gemm_kernel(
    const ushort* __restrict__ WA,   // bf16 [32768][256]
    const float* __restrict__ Wo,    // [256][256]
    const float* __restrict__ bo,    // [256]
    float* __restrict__ out)         // [32768][256]
{
    __shared__ float As[BK][BM + 4];
    __shared__ float Bs[BK][BN + 4];

    const int m0 = blockIdx.x * BM;
    const int n0 = blockIdx.y * BN;

    const int t  = threadIdx.x;
    const int tx = t & 15;
    const int ty = t >> 4;

    float acc[4][4];
    #pragma unroll
    for (int i = 0; i < 4; ++i)
        #pragma unroll
        for (int j = 0; j < 4; ++j) acc[i][j] = 0.f;

    const int lm  = t >> 2;
    const int lk4 = (t & 3) * 4;

    for (int k0 = 0; k0 < HC; k0 += BK) {
        {
            ushort4 v = *(const ushort4*)(WA + (size_t)(m0 + lm) * HC + k0 + lk4);
            As[lk4 + 0][lm] = bf2f(v.x); As[lk4 + 1][lm] = bf2f(v.y);
            As[lk4 + 2][lm] = bf2f(v.z); As[lk4 + 3][lm] = bf2f(v.w);
        }
        {
            float4 v = *(const float4*)(Wo + (size_t)(n0 + lm) * HC + k0 + lk4);
            Bs[lk4 + 0][lm] = v.x; Bs[lk4 + 1][lm] = v.y;
            Bs[lk4 + 2][lm] = v.z; Bs[lk4 + 3][lm] = v.w;
        }
        __syncthreads();
        #pragma unroll
        for (int k = 0; k < BK; ++k) {
            float4 av = *(const float4*)&As[k][ty * 4];
            float4 bv = *(const float4*)&Bs[k][tx * 4];
            float a[4] = {av.x, av.y, av.z, av.w};
            float b[4] = {bv.x, bv.y, bv.z, bv.w};
            #pragma unroll
            for (int i = 0; i < 4; ++i)
                #pragma unroll
                for (int j = 0; j < 4; ++j)
                    acc[i][j] = fmaf(a[i], b[j], acc[i][j]);
        }
        __syncthreads();
    }

    #pragma unroll
    for (int i = 0; i < 4; ++i) {
        const int r = m0 + ty * 4 + i;
        const int n = n0 + tx * 4;
        float4 o;
        o.x = acc[i][0] + bo[n + 0];
        o.y = acc[i][1] + bo[n + 1];
        o.z = acc[i][2] + bo[n + 2];
        o.w = acc[i][3] + bo[n + 3];
        *(float4*)(out + (size_t)r * HC + n) = o;
    }
}

extern "C" void kernel_launch(void* const* d_in, const int* in_sizes, int n_in,
                              void* d_out, int out_size, void* d_ws, size_t ws_size,
                              hipStream_t stream) {
    const float* in_data = (const float*)d_in[0];   // [1,128,256,256]
    const float* mask    = (const float*)d_in[1];   // [1,128,256]
    const float* nb_bias = (const float*)d_in[2];   // [1,8,256,256]
    const float* w_qkv   = (const float*)d_in[3];   // [768,256]
    const float* w_gate  = (const float*)d_in[4];   // [256,256]
    const float* g_bias  = (const float*)d_in[5];   // [256]
    const float* w_o     = (const float*)d_in[6];   // [256,256]
    const float* b_o     = (const float*)d_in[7];   // [256]
    float* out = (float*)d_out;

    // workspace layout (bf16 as ushort)
    ushort* ws = (ushort*)d_ws;
    const size_t per_head = (size_t)B2 * NHEAD * NSEQ * CDIM;  // 8,388,608
    ushort* q_ws  = ws;
    ushort* k_ws  = q_ws + per_head;
    ushort* v_ws  = k_ws + per_head;
    ushort* g_ws  = v_ws + per_head;                // [32768][256]
    ushort* wa_ws = g_ws + (size_t)NROWS * HC;      // [32768][256]

    qkvg_gemm_kernel<<<dim3(NROWS / BM, 1024 / BN), 256, 0, stream>>>(
        in_data, w_qkv, w_gate, g_bias, q_ws, k_ws, v_ws, g_ws);

    attn_mfma_kernel<<<dim3(B2 * NHEAD * 2), 512, 0, stream>>>(
        q_ws, k_ws, v_ws, g_ws, nb_bias, mask, wa_ws);

    out_gemm_kernel<<<dim3(NROWS / BM, HC / BN), 256, 0, stream>>>(
        wa_ws, w_o, b_o, out);
}

// Round 3
// 109.781 us; speedup vs baseline: 5.9556x; 2.9428x over previous
//
#include <hip/hip_runtime.h>
#include <hip/hip_bf16.h>
#include <math.h>

// Problem constants
#define B2      128
#define NSEQ    256
#define DMODEL  256
#define NHEAD   8
#define CDIM    32
#define HC      256
#define NROWS   (B2*NSEQ)    // 32768
#define SCALING 0.17677669529663687f  // 1/sqrt(32)

typedef __attribute__((ext_vector_type(8))) short bf16x8;
typedef __attribute__((ext_vector_type(4))) float f32x4;

static __device__ __forceinline__ ushort f2bf(float f) {
    __hip_bfloat16 b = __float2bfloat16(f);
    ushort r; __builtin_memcpy(&r, &b, 2); return r;
}
static __device__ __forceinline__ float bf2f(ushort u) {
    __hip_bfloat16 b; __builtin_memcpy(&b, &u, 2); return __bfloat162float(b);
}
static __device__ __forceinline__ void gload_lds16(const void* g, void* l) {
    __builtin_amdgcn_global_load_lds((const __attribute__((address_space(1))) void*)g,
                                     (__attribute__((address_space(3))) void*)l, 16, 0, 0);
}

// ---------------- Kernel 0: fp32 -> bf16 conversion ----------------
// X [32768][256], Wqkv [768][256] + Wg [256][256] -> combined [1024][256], Wo [256][256]
__global__ __launch_bounds__(256) void convert_kernel(
    const float* __restrict__ X, const float* __restrict__ Wqkv,
    const float* __restrict__ Wg, const float* __restrict__ Wo,
    ushort* __restrict__ xb, ushort* __restrict__ wqkvgb, ushort* __restrict__ wob)
{
    const int NX = 8388608 / 4, NQ = 196608 / 4, NG = 65536 / 4, NO = 65536 / 4;
    const int total = NX + NQ + NG + NO;
    for (int idx = blockIdx.x * 256 + threadIdx.x; idx < total; idx += gridDim.x * 256) {
        const float* src; ushort* dst; int off;
        if (idx < NX)                { src = X;    dst = xb;              off = idx; }
        else if (idx < NX + NQ)      { src = Wqkv; dst = wqkvgb;          off = idx - NX; }
        else if (idx < NX + NQ + NG) { src = Wg;   dst = wqkvgb + 196608; off = idx - NX - NQ; }
        else                         { src = Wo;   dst = wob;             off = idx - NX - NQ - NG; }
        float4 v = ((const float4*)src)[off];
        union { ushort u[4]; uint2 q; } p;
        p.u[0] = f2bf(v.x); p.u[1] = f2bf(v.y); p.u[2] = f2bf(v.z); p.u[3] = f2bf(v.w);
        *(uint2*)(dst + (size_t)off * 4) = p.q;
    }
}

// ---------------- Kernel 1: MFMA QKV+gate projection ----------------
// P = X @ Wcat^T (M=32768, N=1024, K=256). 128x128 tile, 4 waves, BK=32,
// global_load_lds staging, fused scatter epilogue.
__global__ __launch_bounds__(256) void qkvg_mfma_kernel(
    const ushort* __restrict__ Xb,     // bf16 [32768][256]
    const ushort* __restrict__ Wb,     // bf16 [1024][256] (qkv rows 0-767, gate 768-1023)
    const float* __restrict__ gbias,   // [256]
    ushort* __restrict__ q_ws,         // bf16 [128*8][256][32]
    ushort* __restrict__ k_ws,
    ushort* __restrict__ v_ws,
    ushort* __restrict__ g_ws)         // bf16 [32768][256]
{
    __shared__ ushort Als[128 * 32];   // 8KB
    __shared__ ushort Bls[128 * 32];   // 8KB

    const int tid  = threadIdx.x;
    const int w    = tid >> 6;
    const int lane = tid & 63;
    const int lj   = lane & 15;
    const int lg   = lane >> 4;
    const int wm   = w >> 1;
    const int wn   = w & 1;
    const int m0   = blockIdx.x * 128;
    const int nb   = blockIdx.y;       // 0..7
    const int n0   = nb * 128;

    f32x4 acc[4][4];
    #pragma unroll
    for (int i = 0; i < 4; ++i)
        #pragma unroll
        for (int j = 0; j < 4; ++j) acc[i][j] = (f32x4){0.f, 0.f, 0.f, 0.f};

    const int srow = lane >> 2;        // 0..15 within 16-row chunk
    const int scol = (lane & 3) * 8;   // bf16 element col

    for (int k0 = 0; k0 < 256; k0 += 32) {
        #pragma unroll
        for (int c = 0; c < 2; ++c) {
            const int ci = w * 2 + c;  // 16-row chunk 0..7
            gload_lds16(Xb + (size_t)(m0 + ci * 16 + srow) * 256 + k0 + scol,
                        (char*)Als + ci * 1024);
            gload_lds16(Wb + (size_t)(n0 + ci * 16 + srow) * 256 + k0 + scol,
                        (char*)Bls + ci * 1024);
        }
        __syncthreads();
        bf16x8 af[4], bfr[4];
        #pragma unroll
        for (int i = 0; i < 4; ++i)
            af[i] = *(const bf16x8*)(Als + (wm * 64 + i * 16 + lj) * 32 + lg * 8);
        #pragma unroll
        for (int j = 0; j < 4; ++j)
            bfr[j] = *(const bf16x8*)(Bls + (wn * 64 + j * 16 + lj) * 32 + lg * 8);
        #pragma unroll
        for (int i = 0; i < 4; ++i)
            #pragma unroll
            for (int j = 0; j < 4; ++j)
                acc[i][j] = __builtin_amdgcn_mfma_f32_16x16x32_bf16(af[i], bfr[j], acc[i][j], 0, 0, 0);
        __syncthreads();
    }

    // epilogue: block-uniform segment (q/k/v/gate)
    const int seg = nb >> 1;
    #pragma unroll
    for (int i = 0; i < 4; ++i) {
        #pragma unroll
        for (int r = 0; r < 4; ++r) {
            const int gr  = m0 + wm * 64 + i * 16 + lg * 4 + r;
            const int b2r = gr >> 8;
            const int n   = gr & 255;
            #pragma unroll
            for (int j = 0; j < 4; ++j) {
                const int col = (nb & 1) * 128 + wn * 64 + j * 16 + lj;  // 0..255 in segment
                const float v = acc[i][j][r];
                if (seg == 0) {
                    q_ws[((size_t)(b2r * 8 + (col >> 5)) * 256 + n) * 32 + (col & 31)] =
                        f2bf(v * SCALING);
                } else if (seg == 1) {
                    k_ws[((size_t)(b2r * 8 + (col >> 5)) * 256 + n) * 32 + (col & 31)] = f2bf(v);
                } else if (seg == 2) {
                    v_ws[((size_t)(b2r * 8 + (col >> 5)) * 256 + n) * 32 + (col & 31)] = f2bf(v);
                } else {
                    const float z = v + gbias[col];
                    g_ws[(size_t)gr * 256 + col] = f2bf(1.f / (1.f + __expf(-z)));
                }
            }
        }
    }
}

// ---------------- Kernel 2: MFMA attention (unchanged from r1) ----------------
#define SWZ(c) ((((c) >> 2) & 3) << 5)

__global__ __launch_bounds__(512) void attn_mfma_kernel(
    const ushort* __restrict__ q_ws,
    const ushort* __restrict__ k_ws,
    const ushort* __restrict__ v_ws,
    const ushort* __restrict__ g_ws,
    const float* __restrict__ bias,   // [8][256][256]
    const float* __restrict__ mask,   // [128][256]
    ushort* __restrict__ wa_ws)       // bf16 [32768][256]
{
    __shared__ ushort Ks[256 * 32];
    __shared__ ushort Vt[32 * 256];
    __shared__ ushort Pl[8 * 16 * 64];

    const int tid  = threadIdx.x;
    const int bh   = blockIdx.x >> 1;
    const int half = blockIdx.x & 1;
    const int b2   = bh >> 3;
    const int h    = bh & 7;
    const int w    = tid >> 6;
    const int lane = tid & 63;
    const int lj   = lane & 15;
    const int lg   = lane >> 4;

    {
        const uint4* gk = (const uint4*)(k_ws + (size_t)bh * 8192);
        uint4* sk = (uint4*)Ks;
        sk[tid]       = gk[tid];
        sk[tid + 512] = gk[tid + 512];
    }
    {
        const int cq = tid & 3;
        #pragma unroll
        for (int it = 0; it < 2; ++it) {
            const int n = it * 128 + (tid >> 2);
            uint4 v = *(const uint4*)(v_ws + (size_t)bh * 8192 + n * 32 + cq * 8);
            const ushort* pv = (const ushort*)&v;
            #pragma unroll
            for (int e = 0; e < 8; ++e) {
                const int c = cq * 8 + e;
                const int byte = c * 512 + ((2 * n) ^ SWZ(c));
                Vt[byte >> 1] = pv[e];
            }
        }
    }

    const int q0 = half * 128 + w * 16;
    const bf16x8 qf = *(const bf16x8*)(q_ws + (size_t)bh * 8192 + (size_t)(q0 + lj) * 32 + lg * 8);

    __syncthreads();

    f32x4 acc[16];
    const float* bbase = bias + (size_t)h * 256 * 256;
    const float* mrow  = mask + (size_t)b2 * 256;
    #pragma unroll
    for (int t = 0; t < 16; ++t) {
        const int col = t * 16 + lj;
        const float mterm = (mrow[col] - 1.0f) * 1e9f;
        #pragma unroll
        for (int r = 0; r < 4; ++r) {
            const int qrow = q0 + lg * 4 + r;
            acc[t][r] = bbase[(size_t)qrow * 256 + col] + mterm;
        }
    }

    #pragma unroll
    for (int t = 0; t < 16; ++t) {
        const bf16x8 kf = *(const bf16x8*)(Ks + (t * 16 + lj) * 32 + lg * 8);
        acc[t] = __builtin_amdgcn_mfma_f32_16x16x32_bf16(qf, kf, acc[t], 0, 0, 0);
    }

    float inv[4];
    #pragma unroll
    for (int r = 0; r < 4; ++r) {
        float m = acc[0][r];
        #pragma unroll
        for (int t = 1; t < 16; ++t) m = fmaxf(m, acc[t][r]);
        m = fmaxf(m, __shfl_xor(m, 1));
        m = fmaxf(m, __shfl_xor(m, 2));
        m = fmaxf(m, __shfl_xor(m, 4));
        m = fmaxf(m, __shfl_xor(m, 8));
        float s = 0.f;
        #pragma unroll
        for (int t = 0; t < 16; ++t) {
            float e = __expf(acc[t][r] - m);
            acc[t][r] = e;
            s += e;
        }
        s += __shfl_xor(s, 1);
        s += __shfl_xor(s, 2);
        s += __shfl_xor(s, 4);
        s += __shfl_xor(s, 8);
        inv[r] = 1.0f / s;
    }

    ushort* PlW = Pl + w * 1024;
    f32x4 o0 = {0.f, 0.f, 0.f, 0.f};
    f32x4 o1 = {0.f, 0.f, 0.f, 0.f};
    #pragma unroll
    for (int ch = 0; ch < 4; ++ch) {
        #pragma unroll
        for (int tt = 0; tt < 4; ++tt) {
            const int t = ch * 4 + tt;
            #pragma unroll
            for (int r = 0; r < 4; ++r) {
                const int row  = lg * 4 + r;
                const int byte = row * 128 + ((32 * tt + 2 * lj) ^ (lg << 5));
                PlW[byte >> 1] = f2bf(acc[t][r]);
            }
        }
        #pragma unroll
        for (int kk = 0; kk < 2; ++kk) {
            const int abyte = lj * 128 + ((64 * kk + 16 * lg) ^ SWZ(lj));
            const bf16x8 pa = *(const bf16x8*)(PlW + (abyte >> 1));
            const int ks = ch * 2 + kk;
            {
                const int cr = lj;
                const int vbyte = cr * 512 + ((64 * ks + 16 * lg) ^ SWZ(cr));
                const bf16x8 vb = *(const bf16x8*)(Vt + (vbyte >> 1));
                o0 = __builtin_amdgcn_mfma_f32_16x16x32_bf16(pa, vb, o0, 0, 0, 0);
            }
            {
                const int cr = 16 + lj;
                const int vbyte = cr * 512 + ((64 * ks + 16 * lg) ^ SWZ(cr));
                const bf16x8 vb = *(const bf16x8*)(Vt + (vbyte >> 1));
                o1 = __builtin_amdgcn_mfma_f32_16x16x32_bf16(pa, vb, o1, 0, 0, 0);
            }
        }
    }

    #pragma unroll
    for (int r = 0; r < 4; ++r) {
        const int qrow = q0 + lg * 4 + r;
        const size_t rowbase = ((size_t)(b2 * 256 + qrow)) * 256 + h * 32;
        {
            const float gv = bf2f(g_ws[rowbase + lj]);
            wa_ws[rowbase + lj] = f2bf(o0[r] * inv[r] * gv);
        }
        {
            const float gv = bf2f(g_ws[rowbase + 16 + lj]);
            wa_ws[rowbase + 16 + lj] = f2bf(o1[r] * inv[r] * gv);
        }
    }
}

// ---------------- Kernel 3: MFMA output projection ----------------
// out = WA @ Wo^T + bo (M=32768, N=256, K=256), fp32 out.
__global__ __launch_bounds__(256) void out_mfma_kernel(
    const ushort* __restrict__ WA,   // bf16 [32768][256]
    const ushort* __restrict__ Wob,  // bf16 [256][256]
    const float* __restrict__ bo,    // [256]
    float* __restrict__ out)         // [32768][256]
{
    __shared__ ushort Als[128 * 32];
    __shared__ ushort Bls[128 * 32];

    const int tid  = threadIdx.x;
    const int w    = tid >> 6;
    const int lane = tid & 63;
    const int lj   = lane & 15;
    const int lg   = lane >> 4;
    const int wm   = w >> 1;
    const int wn   = w & 1;
    const int m0   = blockIdx.x * 128;
    const int n0   = blockIdx.y * 128;

    f32x4 acc[4][4];
    #pragma unroll
    for (int i = 0; i < 4; ++i)
        #pragma unroll
        for (int j = 0; j < 4; ++j) acc[i][j] = (f32x4){0.f, 0.f, 0.f, 0.f};

    const int srow = lane >> 2;
    const int scol = (lane & 3) * 8;

    for (int k0 = 0; k0 < 256; k0 += 32) {
        #pragma unroll
        for (int c = 0; c < 2; ++c) {
            const int ci = w * 2 + c;
            gload_lds16(WA  + (size_t)(m0 + ci * 16 + srow) * 256 + k0 + scol,
                        (char*)Als + ci * 1024);
            gload_lds16(Wob + (size_t)(n0 + ci * 16 + srow) * 256 + k0 + scol,
                        (char*)Bls + ci * 1024);
        }
        __syncthreads();
        bf16x8 af[4], bfr[4];
        #pragma unroll
        for (int i = 0; i < 4; ++i)
            af[i] = *(const bf16x8*)(Als + (wm * 64 + i * 16 + lj) * 32 + lg * 8);
        #pragma unroll
        for (int j = 0; j < 4; ++j)
            bfr[j] = *(const bf16x8*)(Bls + (wn * 64 + j * 16 + lj) * 32 + lg * 8);
        #pragma unroll
        for (int i = 0; i < 4; ++i)
            #pragma unroll
            for (int j = 0; j < 4; ++j)
                acc[i][j] = __builtin_amdgcn_mfma_f32_16x16x32_bf16(af[i], bfr[j], acc[i][j], 0, 0, 0);
        __syncthreads();
    }

    #pragma unroll
    for (int i = 0; i < 4; ++i) {
        #pragma unroll
        for (int r = 0; r < 4; ++r) {
            const int gr = m0 + wm * 64 + i * 16 + lg * 4 + r;
            #pragma unroll
            for (int j = 0; j < 4; ++j) {
                const int col = n0 + wn * 64 + j * 16 + lj;
                out[(size_t)gr * 256 + col] = acc[i][j][r] + bo[col];
            }
        }
    }
}

extern "C" void kernel_launch(void* const* d_in, const int* in_sizes, int n_in,
                              void* d_out, int out_size, void* d_ws, size_t ws_size,
                              hipStream_t stream) {
    const float* in_data = (const float*)d_in[0];
    const float* mask    = (const float*)d_in[1];
    const float* nb_bias = (const float*)d_in[2];
    const float* w_qkv   = (const float*)d_in[3];
    const float* w_gate  = (const float*)d_in[4];
    const float* g_bias  = (const float*)d_in[5];
    const float* w_o     = (const float*)d_in[6];
    const float* b_o     = (const float*)d_in[7];
    float* out = (float*)d_out;

    ushort* ws = (ushort*)d_ws;
    const size_t per_head = (size_t)B2 * NHEAD * NSEQ * CDIM;  // 8,388,608
    ushort* q_ws   = ws;
    ushort* k_ws   = q_ws + per_head;
    ushort* v_ws   = k_ws + per_head;
    ushort* g_ws   = v_ws + per_head;                 // [32768][256]
    ushort* wa_ws  = g_ws + (size_t)NROWS * HC;
    ushort* xb     = wa_ws + (size_t)NROWS * HC;      // [32768][256]
    ushort* wqkvgb = xb + (size_t)NROWS * DMODEL;     // [1024][256]
    ushort* wob    = wqkvgb + 1024 * 256;             // [256][256]

    convert_kernel<<<dim3(2048), 256, 0, stream>>>(
        in_data, w_qkv, w_gate, w_o, xb, wqkvgb, wob);

    qkvg_mfma_kernel<<<dim3(NROWS / 128, 8), 256, 0, stream>>>(
        xb, wqkvgb, g_bias, q_ws, k_ws, v_ws, g_ws);

    attn_mfma_kernel<<<dim3(B2 * NHEAD * 2), 512, 0, stream>>>(
        q_ws, k_ws, v_ws, g_ws, nb_bias, mask, wa_ws);

    out_mfma_kernel<<<dim3(NROWS / 128, 2), 256, 0, stream>>>(
        wa_ws, wob, b_o, out);
}